// Round 7
// baseline (3372.345 us; speedup 1.0000x reference)
//
#include <hip/hip_runtime.h>
#include <hip/hip_bf16.h>
#include <stdint.h>

#define NV 100000   // nodes
#define NT 8        // edge types
#define NE 400000   // edges per type
#define ND 128      // feature dim
#define NTV (NT * NV)                 // 800000 (t,v) pairs
#define SC1B ((NTV + 1023) / 1024)    // 782 scan blocks
#define XCVT ((NV * ND / 8) / 256)    // 6250 blocks for x-convert

typedef float  f32x4  __attribute__((ext_vector_type(4)));
typedef short  bf16x8 __attribute__((ext_vector_type(8)));

static __device__ __forceinline__ unsigned short f2bf(float f) {
    unsigned u = __float_as_uint(f);
    u += 0x7fffu + ((u >> 16) & 1u);   // RNE
    return (unsigned short)(u >> 16);
}

// degree counts for src (cs) and dest (cd); 4 edges/thread via int4
__global__ __launch_bounds__(256) void k_count(const int* __restrict__ edges,
                                               unsigned* __restrict__ cs,
                                               unsigned* __restrict__ cd) {
    int i = blockIdx.x * 256 + threadIdx.x;          // NT*NE/4 threads
    if (i >= NT * NE / 4) return;
    int t = i / (NE / 4);
    int e = (i - t * (NE / 4)) * 4;
    const int* base = edges + (size_t)t * 2 * NE;
    int4 s4 = *(const int4*)&base[e];
    int4 d4 = *(const int4*)&base[NE + e];
    unsigned* cst = cs + t * NV;
    unsigned* cdt = cd + t * NV;
    atomicAdd(&cst[s4.x], 1u); atomicAdd(&cst[s4.y], 1u);
    atomicAdd(&cst[s4.z], 1u); atomicAdd(&cst[s4.w], 1u);
    atomicAdd(&cdt[d4.x], 1u); atomicAdd(&cdt[d4.y], 1u);
    atomicAdd(&cdt[d4.z], 1u); atomicAdd(&cdt[d4.w], 1u);
}

// ---- exclusive scan of cd (800000 u32) -> off ----
__global__ __launch_bounds__(256) void k_scan1(const unsigned* __restrict__ cnt,
                                               unsigned* __restrict__ off,
                                               unsigned* __restrict__ bsum) {
    __shared__ unsigned sm[256];
    int tid  = threadIdx.x;
    int base = blockIdx.x * 1024 + tid * 4;
    unsigned v0 = (base + 0 < NTV) ? cnt[base + 0] : 0u;
    unsigned v1 = (base + 1 < NTV) ? cnt[base + 1] : 0u;
    unsigned v2 = (base + 2 < NTV) ? cnt[base + 2] : 0u;
    unsigned v3 = (base + 3 < NTV) ? cnt[base + 3] : 0u;
    unsigned s4 = v0 + v1 + v2 + v3;
    sm[tid] = s4;
    __syncthreads();
    for (int d = 1; d < 256; d <<= 1) {
        unsigned tv = (tid >= d) ? sm[tid - d] : 0u;
        __syncthreads();
        sm[tid] += tv;
        __syncthreads();
    }
    unsigned excl = sm[tid] - s4;
    if (tid == 255) bsum[blockIdx.x] = sm[255];
    if (base + 0 < NTV) off[base + 0] = excl;
    if (base + 1 < NTV) off[base + 1] = excl + v0;
    if (base + 2 < NTV) off[base + 2] = excl + v0 + v1;
    if (base + 3 < NTV) off[base + 3] = excl + v0 + v1 + v2;
}

__global__ __launch_bounds__(1024) void k_scan2(unsigned* __restrict__ bsum) {
    __shared__ unsigned sm[1024];
    int tid = threadIdx.x;
    unsigned v = (tid < SC1B) ? bsum[tid] : 0u;
    sm[tid] = v;
    __syncthreads();
    for (int d = 1; d < 1024; d <<= 1) {
        unsigned tv = (tid >= d) ? sm[tid - d] : 0u;
        __syncthreads();
        sm[tid] += tv;
        __syncthreads();
    }
    if (tid < SC1B) bsum[tid] = sm[tid] - v;   // exclusive
}

// scan finalize + cursor copy + inv_ns (fused)
__global__ __launch_bounds__(256) void k_scan3(unsigned* __restrict__ off,
                                               const unsigned* __restrict__ bsum,
                                               unsigned* __restrict__ cursor,
                                               unsigned* __restrict__ cs) {
    int i = blockIdx.x * 256 + threadIdx.x;
    if (i < NTV) {
        unsigned v = off[i] + bsum[i >> 10];
        off[i]    = v;
        cursor[i] = v;
        unsigned a = cs[i];
        ((float*)cs)[i] = rsqrtf((float)(a > 1u ? a : 1u));
    }
    if (i == 0) off[NTV] = (unsigned)(NT * NE);
}

// fused converts: blocks [0,XCVT) do x f32->bf16; rest do W transpose+bf16
__global__ __launch_bounds__(256) void k_cvt(const float* __restrict__ x,
                                             unsigned short* __restrict__ xb,
                                             const float* __restrict__ W,
                                             unsigned short* __restrict__ Wt) {
    if (blockIdx.x < XCVT) {
        int i = blockIdx.x * 256 + threadIdx.x;
        const float4 a = *(const float4*)&x[(size_t)i * 8];
        const float4 b = *(const float4*)&x[(size_t)i * 8 + 4];
        union { unsigned short us[8]; uint4 v; } pk;
        pk.us[0] = f2bf(a.x); pk.us[1] = f2bf(a.y);
        pk.us[2] = f2bf(a.z); pk.us[3] = f2bf(a.w);
        pk.us[4] = f2bf(b.x); pk.us[5] = f2bf(b.y);
        pk.us[6] = f2bf(b.z); pk.us[7] = f2bf(b.w);
        *(uint4*)&xb[(size_t)i * 8] = pk.v;
    } else {
        int i = (blockIdx.x - XCVT) * 256 + threadIdx.x;   // NT*ND*ND = 131072
        int t = i >> 14;
        int r = i & 16383;
        int col = r >> 7;
        int k   = r & 127;
        Wt[i] = f2bf(W[((size_t)t * 128 + k) * 128 + col]);
    }
}

// CSR fill: entry = {src | (dest&15)<<17, inv_ns[t][src]}; 4 edges/thread.
// localrow (dest&15) is valid because dest-blocks are 16-aligned in k_fused.
__global__ __launch_bounds__(256) void k_fill(const int* __restrict__ edges,
                                              const float* __restrict__ inv_ns,
                                              unsigned* __restrict__ cursor,
                                              uint2* __restrict__ elist2) {
    int i = blockIdx.x * 256 + threadIdx.x;          // NT*NE/4 threads
    if (i >= NT * NE / 4) return;
    int t = i / (NE / 4);
    int e = (i - t * (NE / 4)) * 4;
    const int* base = edges + (size_t)t * 2 * NE;
    int4 s4 = *(const int4*)&base[e];
    int4 d4 = *(const int4*)&base[NE + e];
    const float* insb = inv_ns + (size_t)t * NV;
    unsigned*    curt = cursor + t * NV;
    unsigned p0 = atomicAdd(&curt[d4.x], 1u);
    elist2[p0] = make_uint2((unsigned)s4.x | (((unsigned)d4.x & 15u) << 17),
                            __float_as_uint(insb[s4.x]));
    unsigned p1 = atomicAdd(&curt[d4.y], 1u);
    elist2[p1] = make_uint2((unsigned)s4.y | (((unsigned)d4.y & 15u) << 17),
                            __float_as_uint(insb[s4.y]));
    unsigned p2 = atomicAdd(&curt[d4.z], 1u);
    elist2[p2] = make_uint2((unsigned)s4.z | (((unsigned)d4.z & 15u) << 17),
                            __float_as_uint(insb[s4.z]));
    unsigned p3 = atomicAdd(&curt[d4.w], 1u);
    elist2[p3] = make_uint2((unsigned)s4.w | (((unsigned)d4.w & 15u) << 17),
                            __float_as_uint(insb[s4.w]));
}

// two bf16 from one dword, scaled, ds-atomic-added with rotate swizzle
static __device__ __forceinline__ void ds_acc2(float* __restrict__ aw, int rot,
                                               int kb, unsigned cw, float sns) {
    atomicAdd(&aw[(kb + rot) & 31],     __uint_as_float(cw << 16) * sns);
    atomicAdd(&aw[(kb + 1 + rot) & 31], __uint_as_float(cw & 0xffff0000u) * sns);
}

// fused gather + (agg * inv_nd) @ W_t, accumulated over t in MFMA regs.
// Edge-streaming gather: per wave, the 16-row CSR range is CONTIGUOUS in
// elist2; process 16 edges/batch (lane = slot j = lane&15, chunk g = lane>>4;
// 4 lanes cover one edge's 256B row). Accumulate into per-wave LDS tile via
// native ds_add_f32. Swizzle: feature f (sec=f>>5, kk=f&31) lives at word
// sec*32 + ((kk + r + 16*sec)&31) of row r  -> <=2-way bank aliasing.
__global__ __launch_bounds__(256, 4) void k_fused(
    const unsigned short* __restrict__ xb, const unsigned short* __restrict__ Wt,
    const unsigned* __restrict__ off, const uint2* __restrict__ elist2,
    const float* __restrict__ bias, float* __restrict__ out)
{
    __shared__ float agg[4][16][128];   // 32 KB, per-wave 8KB region
    const int lane  = threadIdx.x & 63;
    const int wid   = threadIdx.x >> 6;
    const int row0  = blockIdx.x * 64 + wid * 16;
    const int arow  = lane & 15;        // edge slot in gather; A-row in MFMA
    const int g     = lane >> 4;        // 64B chunk in gather; k-group in MFMA
    const int myrow = row0 + arow;

    f32x4 acc[8];
#pragma unroll
    for (int cf = 0; cf < 8; ++cf) acc[cf] = (f32x4){0.f, 0.f, 0.f, 0.f};

    // clamped 16-row range (NV % 16 == 0: ranges are all-valid or all-empty)
    const int rlo = (row0 < NV) ? row0 : NV;
    const int rhi = (row0 + 16 < NV) ? row0 + 16 : NV;

    for (int t = 0; t < NT; ++t) {
        // zero my wave's agg region (2048 floats, conflict-free b128 stores)
        float4* z = (float4*)&agg[wid][0][0];
#pragma unroll
        for (int it = 0; it < 8; ++it) z[it * 64 + lane] = make_float4(0.f, 0.f, 0.f, 0.f);
        __asm__ volatile("s_waitcnt lgkmcnt(0)" ::: "memory");

        const unsigned e0 = off[t * NV + rlo];
        const unsigned e1 = off[t * NV + rhi];

        for (unsigned base = e0; base < e1; base += 16) {
            unsigned e = base + (unsigned)arow;
            if (e < e1) {
                uint2 p   = elist2[e];
                int   src = (int)(p.x & 0x1FFFFu);
                int   r   = (int)(p.x >> 17);
                float sns = __uint_as_float(p.y);
                const uint4* xp = (const uint4*)(xb + (size_t)src * ND) + g * 4;
                uint4 c0 = xp[0], c1 = xp[1], c2 = xp[2], c3 = xp[3];
                float* aw = &agg[wid][r][g * 32];
                const int rot = (r + 16 * g) & 31;
                ds_acc2(aw, rot, 0,  c0.x, sns); ds_acc2(aw, rot, 2,  c0.y, sns);
                ds_acc2(aw, rot, 4,  c0.z, sns); ds_acc2(aw, rot, 6,  c0.w, sns);
                ds_acc2(aw, rot, 8,  c1.x, sns); ds_acc2(aw, rot, 10, c1.y, sns);
                ds_acc2(aw, rot, 12, c1.z, sns); ds_acc2(aw, rot, 14, c1.w, sns);
                ds_acc2(aw, rot, 16, c2.x, sns); ds_acc2(aw, rot, 18, c2.y, sns);
                ds_acc2(aw, rot, 20, c2.z, sns); ds_acc2(aw, rot, 22, c2.w, sns);
                ds_acc2(aw, rot, 24, c3.x, sns); ds_acc2(aw, rot, 26, c3.y, sns);
                ds_acc2(aw, rot, 28, c3.z, sns); ds_acc2(aw, rot, 30, c3.w, sns);
            }
        }
        __asm__ volatile("s_waitcnt lgkmcnt(0)" ::: "memory");

        // inv_nd for my A-row (dest-degree from off diff)
        int ci = t * NV + (myrow < NV ? myrow : NV - 1);
        unsigned dd = off[ci + 1] - off[ci];
        float snd = rsqrtf((float)(dd > 1u ? dd : 1u));

        // A-frag from LDS (inverse swizzle), B-frag from Wt, 32 MFMAs
#pragma unroll
        for (int ks = 0; ks < 4; ++ks) {
            union { unsigned short u[8]; bf16x8 v; } af;
            const int rot2 = (arow + 16 * ks) & 31;
#pragma unroll
            for (int j = 0; j < 8; ++j) {
                float val = agg[wid][arow][ks * 32 + ((g * 8 + j + rot2) & 31)];
                af.u[j] = f2bf(val * snd);
            }
#pragma unroll
            for (int cf = 0; cf < 8; ++cf) {
                const bf16x8 bf = *(const bf16x8*)&Wt[((size_t)(t * 128 + cf * 16 + arow)) * 128 + ks * 32 + g * 8];
                acc[cf] = __builtin_amdgcn_mfma_f32_16x16x32_bf16(af.v, bf, acc[cf], 0, 0, 0);
            }
        }
    }

    // C/D layout: col = lane&15, row = (lane>>4)*4 + i  [HW-verified]
#pragma unroll
    for (int i2 = 0; i2 < 4; ++i2) {
        int row = row0 + g * 4 + i2;
        if (row < NV) {
#pragma unroll
            for (int cf = 0; cf < 8; ++cf)
                out[(size_t)row * ND + cf * 16 + arow] = acc[cf][i2] + bias[cf * 16 + arow];
        }
    }
}

extern "C" void kernel_launch(void* const* d_in, const int* in_sizes, int n_in,
                              void* d_out, int out_size, void* d_ws, size_t ws_size,
                              hipStream_t stream) {
    const float* x     = (const float*)d_in[0];
    const int*   edges = (const int*)d_in[1];
    const float* W     = (const float*)d_in[2];
    const float* b     = (const float*)d_in[3];
    float*       out   = (float*)d_out;

    // ws layout: xb (25.6MB) | Wt (256KB) | elist2 (25.6MB, 8B-aligned) |
    //            cs | cd | off(+1) | bsum | cursor
    unsigned short* xb     = (unsigned short*)d_ws;
    unsigned short* Wt     = xb + (size_t)NV * ND;
    uint2*          elist2 = (uint2*)(Wt + (size_t)NT * ND * ND);
    unsigned*       cs     = (unsigned*)(elist2 + (size_t)NT * NE);
    unsigned*       cd     = cs + NTV;
    unsigned*       off    = cd + NTV;          // NTV+1
    unsigned*       bsum   = off + NTV + 1;     // 1024
    unsigned*       cursor = bsum + 1024;

    const size_t need = (size_t)NV * ND * 2 + (size_t)NT * ND * ND * 2 +
                        (size_t)NT * NE * 8 +
                        ((size_t)3 * NTV + (NTV + 1) + 1024) * 4;
    if (ws_size < need) return;

    hipMemsetAsync(cs, 0, (size_t)2 * NTV * sizeof(unsigned), stream);
    k_count<<<(NT * NE / 4 + 255) / 256, 256, 0, stream>>>(edges, cs, cd);
    k_scan1<<<SC1B, 256, 0, stream>>>(cd, off, bsum);
    k_scan2<<<1, 1024, 0, stream>>>(bsum);
    k_scan3<<<(NTV + 255) / 256, 256, 0, stream>>>(off, bsum, cursor, cs);
    k_cvt<<<XCVT + (NT * ND * ND) / 256, 256, 0, stream>>>(x, xb, W, Wt);
    k_fill<<<(NT * NE / 4 + 255) / 256, 256, 0, stream>>>(edges, (const float*)cs, cursor, elist2);
    k_fused<<<(NV + 63) / 64, 256, 0, stream>>>(xb, Wt, off, elist2, b, out);
}

// Round 8
// 836.290 us; speedup vs baseline: 4.0325x; 4.0325x over previous
//
#include <hip/hip_runtime.h>
#include <hip/hip_bf16.h>
#include <stdint.h>

#define NV 100000   // nodes
#define NT 8        // edge types
#define NE 400000   // edges per type
#define ND 128      // feature dim
#define NTV (NT * NV)                 // 800000 (t,v) pairs
#define SC1B ((NTV + 1023) / 1024)    // 782 scan blocks
#define XCVT ((NV * ND / 8) / 256)    // 6250 blocks for x-convert

typedef float  f32x4  __attribute__((ext_vector_type(4)));
typedef short  bf16x8 __attribute__((ext_vector_type(8)));

static __device__ __forceinline__ unsigned short f2bf(float f) {
    unsigned u = __float_as_uint(f);
    u += 0x7fffu + ((u >> 16) & 1u);   // RNE
    return (unsigned short)(u >> 16);
}

// degree counts for src (cs) and dest (cd); 4 edges/thread via int4
__global__ __launch_bounds__(256) void k_count(const int* __restrict__ edges,
                                               unsigned* __restrict__ cs,
                                               unsigned* __restrict__ cd) {
    int i = blockIdx.x * 256 + threadIdx.x;          // NT*NE/4 threads
    if (i >= NT * NE / 4) return;
    int t = i / (NE / 4);
    int e = (i - t * (NE / 4)) * 4;
    const int* base = edges + (size_t)t * 2 * NE;
    int4 s4 = *(const int4*)&base[e];
    int4 d4 = *(const int4*)&base[NE + e];
    unsigned* cst = cs + t * NV;
    unsigned* cdt = cd + t * NV;
    atomicAdd(&cst[s4.x], 1u); atomicAdd(&cst[s4.y], 1u);
    atomicAdd(&cst[s4.z], 1u); atomicAdd(&cst[s4.w], 1u);
    atomicAdd(&cdt[d4.x], 1u); atomicAdd(&cdt[d4.y], 1u);
    atomicAdd(&cdt[d4.z], 1u); atomicAdd(&cdt[d4.w], 1u);
}

// ---- exclusive scan of cd (800000 u32) -> off ----
__global__ __launch_bounds__(256) void k_scan1(const unsigned* __restrict__ cnt,
                                               unsigned* __restrict__ off,
                                               unsigned* __restrict__ bsum) {
    __shared__ unsigned sm[256];
    int tid  = threadIdx.x;
    int base = blockIdx.x * 1024 + tid * 4;
    unsigned v0 = (base + 0 < NTV) ? cnt[base + 0] : 0u;
    unsigned v1 = (base + 1 < NTV) ? cnt[base + 1] : 0u;
    unsigned v2 = (base + 2 < NTV) ? cnt[base + 2] : 0u;
    unsigned v3 = (base + 3 < NTV) ? cnt[base + 3] : 0u;
    unsigned s4 = v0 + v1 + v2 + v3;
    sm[tid] = s4;
    __syncthreads();
    for (int d = 1; d < 256; d <<= 1) {
        unsigned tv = (tid >= d) ? sm[tid - d] : 0u;
        __syncthreads();
        sm[tid] += tv;
        __syncthreads();
    }
    unsigned excl = sm[tid] - s4;
    if (tid == 255) bsum[blockIdx.x] = sm[255];
    if (base + 0 < NTV) off[base + 0] = excl;
    if (base + 1 < NTV) off[base + 1] = excl + v0;
    if (base + 2 < NTV) off[base + 2] = excl + v0 + v1;
    if (base + 3 < NTV) off[base + 3] = excl + v0 + v1 + v2;
}

__global__ __launch_bounds__(1024) void k_scan2(unsigned* __restrict__ bsum) {
    __shared__ unsigned sm[1024];
    int tid = threadIdx.x;
    unsigned v = (tid < SC1B) ? bsum[tid] : 0u;
    sm[tid] = v;
    __syncthreads();
    for (int d = 1; d < 1024; d <<= 1) {
        unsigned tv = (tid >= d) ? sm[tid - d] : 0u;
        __syncthreads();
        sm[tid] += tv;
        __syncthreads();
    }
    if (tid < SC1B) bsum[tid] = sm[tid] - v;   // exclusive
}

// scan finalize + cursor copy + inv_ns (fused)
__global__ __launch_bounds__(256) void k_scan3(unsigned* __restrict__ off,
                                               const unsigned* __restrict__ bsum,
                                               unsigned* __restrict__ cursor,
                                               unsigned* __restrict__ cs) {
    int i = blockIdx.x * 256 + threadIdx.x;
    if (i < NTV) {
        unsigned v = off[i] + bsum[i >> 10];
        off[i]    = v;
        cursor[i] = v;
        unsigned a = cs[i];
        ((float*)cs)[i] = rsqrtf((float)(a > 1u ? a : 1u));
    }
    if (i == 0) off[NTV] = (unsigned)(NT * NE);
}

// fused converts: blocks [0,XCVT) do x f32->bf16; rest do W transpose+bf16
__global__ __launch_bounds__(256) void k_cvt(const float* __restrict__ x,
                                             unsigned short* __restrict__ xb,
                                             const float* __restrict__ W,
                                             unsigned short* __restrict__ Wt) {
    if (blockIdx.x < XCVT) {
        int i = blockIdx.x * 256 + threadIdx.x;
        const float4 a = *(const float4*)&x[(size_t)i * 8];
        const float4 b = *(const float4*)&x[(size_t)i * 8 + 4];
        union { unsigned short us[8]; uint4 v; } pk;
        pk.us[0] = f2bf(a.x); pk.us[1] = f2bf(a.y);
        pk.us[2] = f2bf(a.z); pk.us[3] = f2bf(a.w);
        pk.us[4] = f2bf(b.x); pk.us[5] = f2bf(b.y);
        pk.us[6] = f2bf(b.z); pk.us[7] = f2bf(b.w);
        *(uint4*)&xb[(size_t)i * 8] = pk.v;
    } else {
        int i = (blockIdx.x - XCVT) * 256 + threadIdx.x;   // NT*ND*ND = 131072
        int t = i >> 14;
        int r = i & 16383;
        int col = r >> 7;
        int k   = r & 127;
        Wt[i] = f2bf(W[((size_t)t * 128 + k) * 128 + col]);
    }
}

// CSR fill (round-7 proven): entry = {src | (dest&15)<<17, inv_ns[t][src]}
__global__ __launch_bounds__(256) void k_fill(const int* __restrict__ edges,
                                              const float* __restrict__ inv_ns,
                                              unsigned* __restrict__ cursor,
                                              uint2* __restrict__ elist2) {
    int i = blockIdx.x * 256 + threadIdx.x;          // NT*NE/4 threads
    if (i >= NT * NE / 4) return;
    int t = i / (NE / 4);
    int e = (i - t * (NE / 4)) * 4;
    const int* base = edges + (size_t)t * 2 * NE;
    int4 s4 = *(const int4*)&base[e];
    int4 d4 = *(const int4*)&base[NE + e];
    const float* insb = inv_ns + (size_t)t * NV;
    unsigned*    curt = cursor + t * NV;
    unsigned p0 = atomicAdd(&curt[d4.x], 1u);
    elist2[p0] = make_uint2((unsigned)s4.x | (((unsigned)d4.x & 15u) << 17),
                            __float_as_uint(insb[s4.x]));
    unsigned p1 = atomicAdd(&curt[d4.y], 1u);
    elist2[p1] = make_uint2((unsigned)s4.y | (((unsigned)d4.y & 15u) << 17),
                            __float_as_uint(insb[s4.y]));
    unsigned p2 = atomicAdd(&curt[d4.z], 1u);
    elist2[p2] = make_uint2((unsigned)s4.z | (((unsigned)d4.z & 15u) << 17),
                            __float_as_uint(insb[s4.z]));
    unsigned p3 = atomicAdd(&curt[d4.w], 1u);
    elist2[p3] = make_uint2((unsigned)s4.w | (((unsigned)d4.w & 15u) << 17),
                            __float_as_uint(insb[s4.w]));
}

#define ACC8(dst, c, s)                                                      \
    do {                                                                     \
        (dst)[0] = fmaf(__uint_as_float((c).x << 16), (s), (dst)[0]);        \
        (dst)[1] = fmaf(__uint_as_float((c).x & 0xffff0000u), (s), (dst)[1]);\
        (dst)[2] = fmaf(__uint_as_float((c).y << 16), (s), (dst)[2]);        \
        (dst)[3] = fmaf(__uint_as_float((c).y & 0xffff0000u), (s), (dst)[3]);\
        (dst)[4] = fmaf(__uint_as_float((c).z << 16), (s), (dst)[4]);        \
        (dst)[5] = fmaf(__uint_as_float((c).z & 0xffff0000u), (s), (dst)[5]);\
        (dst)[6] = fmaf(__uint_as_float((c).w << 16), (s), (dst)[6]);        \
        (dst)[7] = fmaf(__uint_as_float((c).w & 0xffff0000u), (s), (dst)[7]);\
    } while (0)

// fused gather + (agg * inv_nd) @ W_t, accumulated over t in MFMA regs.
// One wave per 16 dest rows (grid NV/16, fine-grained balance).
// TWO edge types interleaved per pass: two independent elist2->row load
// chains per lane. Per-type edge order and t-order preserved -> output
// bit-identical to round 5 (absmax sentinel 0.0078125).
__global__ __launch_bounds__(64, 3) void k_fused(
    const unsigned short* __restrict__ xb, const unsigned short* __restrict__ Wt,
    const unsigned* __restrict__ off, const uint2* __restrict__ elist2,
    const float* __restrict__ bias, float* __restrict__ out)
{
    const int lane  = threadIdx.x;      // 0..63
    const int row0  = blockIdx.x * 16;
    const int arow  = lane & 15;
    const int g     = lane >> 4;
    const int myrow = row0 + arow;      // NV % 16 == 0: always valid

    f32x4 acc[8];
#pragma unroll
    for (int cf = 0; cf < 8; ++cf) acc[cf] = (f32x4){0.f, 0.f, 0.f, 0.f};

#pragma unroll
    for (int p = 0; p < 4; ++p) {
        const int t0 = 2 * p, t1 = t0 + 1;
        float ga0[32], ga1[32];
#pragma unroll
        for (int j = 0; j < 32; ++j) { ga0[j] = 0.f; ga1[j] = 0.f; }

        unsigned e  = off[t0 * NV + myrow];
        unsigned e1 = off[t0 * NV + myrow + 1];
        unsigned f  = off[t1 * NV + myrow];
        unsigned f1 = off[t1 * NV + myrow + 1];
        const unsigned de = e1 - e, df = f1 - f;

        while (e < e1 || f < f1) {
            const bool ae = (e < e1);
            const bool af2 = (f < f1);
            uint2 pe, pf;
            if (ae)  pe = elist2[e];
            if (af2) pf = elist2[f];
            uint4 a0, a1, a2, a3, b0, b1, b2, b3;
            if (ae) {
                const uint4* xp = (const uint4*)(xb + (size_t)(pe.x & 0x1FFFFu) * ND) + g;
                a0 = xp[0]; a1 = xp[4]; a2 = xp[8]; a3 = xp[12];
            }
            if (af2) {
                const uint4* xq = (const uint4*)(xb + (size_t)(pf.x & 0x1FFFFu) * ND) + g;
                b0 = xq[0]; b1 = xq[4]; b2 = xq[8]; b3 = xq[12];
            }
            if (ae) {
                float s = __uint_as_float(pe.y);
                ACC8(ga0 + 0,  a0, s); ACC8(ga0 + 8,  a1, s);
                ACC8(ga0 + 16, a2, s); ACC8(ga0 + 24, a3, s);
                ++e;
            }
            if (af2) {
                float s = __uint_as_float(pf.y);
                ACC8(ga1 + 0,  b0, s); ACC8(ga1 + 8,  b1, s);
                ACC8(ga1 + 16, b2, s); ACC8(ga1 + 24, b3, s);
                ++f;
            }
        }

        const float snd0 = rsqrtf((float)(de > 1u ? de : 1u));
        const float snd1 = rsqrtf((float)(df > 1u ? df : 1u));
        // MFMA t0 fully, then t1 (same order as sequential-t round 5)
#pragma unroll
        for (int ks = 0; ks < 4; ++ks) {
            union { unsigned short u[8]; bf16x8 v; } af;
#pragma unroll
            for (int j = 0; j < 8; ++j) af.u[j] = f2bf(ga0[ks * 8 + j] * snd0);
#pragma unroll
            for (int cf = 0; cf < 8; ++cf) {
                const bf16x8 bf = *(const bf16x8*)&Wt[((size_t)(t0 * 128 + cf * 16 + arow)) * 128 + ks * 32 + g * 8];
                acc[cf] = __builtin_amdgcn_mfma_f32_16x16x32_bf16(af.v, bf, acc[cf], 0, 0, 0);
            }
        }
#pragma unroll
        for (int ks = 0; ks < 4; ++ks) {
            union { unsigned short u[8]; bf16x8 v; } af;
#pragma unroll
            for (int j = 0; j < 8; ++j) af.u[j] = f2bf(ga1[ks * 8 + j] * snd1);
#pragma unroll
            for (int cf = 0; cf < 8; ++cf) {
                const bf16x8 bf = *(const bf16x8*)&Wt[((size_t)(t1 * 128 + cf * 16 + arow)) * 128 + ks * 32 + g * 8];
                acc[cf] = __builtin_amdgcn_mfma_f32_16x16x32_bf16(af.v, bf, acc[cf], 0, 0, 0);
            }
        }
    }

    // C/D layout: col = lane&15, row = (lane>>4)*4 + i  [HW-verified]
#pragma unroll
    for (int i2 = 0; i2 < 4; ++i2) {
        int row = row0 + g * 4 + i2;
#pragma unroll
        for (int cf = 0; cf < 8; ++cf)
            out[(size_t)row * ND + cf * 16 + arow] = acc[cf][i2] + bias[cf * 16 + arow];
    }
}

extern "C" void kernel_launch(void* const* d_in, const int* in_sizes, int n_in,
                              void* d_out, int out_size, void* d_ws, size_t ws_size,
                              hipStream_t stream) {
    const float* x     = (const float*)d_in[0];
    const int*   edges = (const int*)d_in[1];
    const float* W     = (const float*)d_in[2];
    const float* b     = (const float*)d_in[3];
    float*       out   = (float*)d_out;

    // ws layout: xb (25.6MB) | Wt (256KB) | elist2 (25.6MB, 8B-aligned) |
    //            cs | cd | off(+1) | bsum | cursor
    unsigned short* xb     = (unsigned short*)d_ws;
    unsigned short* Wt     = xb + (size_t)NV * ND;
    uint2*          elist2 = (uint2*)(Wt + (size_t)NT * ND * ND);
    unsigned*       cs     = (unsigned*)(elist2 + (size_t)NT * NE);
    unsigned*       cd     = cs + NTV;
    unsigned*       off    = cd + NTV;          // NTV+1
    unsigned*       bsum   = off + NTV + 1;     // 1024
    unsigned*       cursor = bsum + 1024;

    const size_t need = (size_t)NV * ND * 2 + (size_t)NT * ND * ND * 2 +
                        (size_t)NT * NE * 8 +
                        ((size_t)3 * NTV + (NTV + 1) + 1024) * 4;
    if (ws_size < need) return;

    hipMemsetAsync(cs, 0, (size_t)2 * NTV * sizeof(unsigned), stream);
    k_count<<<(NT * NE / 4 + 255) / 256, 256, 0, stream>>>(edges, cs, cd);
    k_scan1<<<SC1B, 256, 0, stream>>>(cd, off, bsum);
    k_scan2<<<1, 1024, 0, stream>>>(bsum);
    k_scan3<<<(NTV + 255) / 256, 256, 0, stream>>>(off, bsum, cursor, cs);
    k_cvt<<<XCVT + (NT * ND * ND) / 256, 256, 0, stream>>>(x, xb, W, Wt);
    k_fill<<<(NT * NE / 4 + 255) / 256, 256, 0, stream>>>(edges, (const float*)cs, cursor, elist2);
    k_fused<<<NV / 16, 64, 0, stream>>>(xb, Wt, off, elist2, b, out);
}